// Round 8
// baseline (25.724 us; speedup 1.0000x reference)
//
#include <hip/hip_runtime.h>
#include <math.h>

typedef __attribute__((ext_vector_type(8))) short bf16x8;
typedef __attribute__((ext_vector_type(4))) float f32x4;

#define N_CAM 6
#define C_IN 256
#define C_OUT 80
#define FH 32
#define FW 88
#define NXG 200
#define NYG 200
#define S_SPATIAL (NXG*NYG)        // 40000
#define POS_PER_CAM (FH*FW)        // 2816
#define NPOS (N_CAM*POS_PER_CAM)   // 16896
#define TPOS 32                    // positions per k_fconv block

__device__ __forceinline__ unsigned short f2bf(float f) {   // RTN-even fp32->bf16
    unsigned u = __builtin_bit_cast(unsigned, f);
    u += 0x7fffu + ((u >> 16) & 1u);
    return (unsigned short)(u >> 16);
}
__device__ __forceinline__ float bf2f(unsigned short u) {
    return __builtin_bit_cast(float, ((unsigned)u) << 16);
}

// ---------------- kernel 1: fused weight-prep + convert/transpose + MFMA ----------------
// 528 blocks x 128 thr (2 waves); block = 32-pos tile x all 256 ch.
// Stage A-fragments (16 KB) + BN-folded B-fragments (40 KB) in LDS, then
// wave wv: 8 A-frags + 40 B-frags (ds_read_b128) -> 40 MFMA -> feat2b bf16.
__global__ __launch_bounds__(128) void k_fconv(const float* __restrict__ feat,
                                               const float* __restrict__ conv_w,
                                               const float* __restrict__ gamma,
                                               const float* __restrict__ var,
                                               unsigned short* __restrict__ feat2b) {
    __shared__ uint4 sfo[1024];              // 16 KB: 2 mtiles x 8 ks x 64 lanes
    __shared__ uint4 wfrag[2560];            // 40 KB: 40 frags x 64 lanes
    int b = blockIdx.x, t = threadIdx.x;     // 528 = 6 cams * 88 tiles
    int n = b / 88, p0 = (b % 88) * TPOS;
    const float* fn = feat + (size_t)n * C_IN * POS_PER_CAM + p0;
    uint2* sfo2 = reinterpret_cast<uint2*>(sfo);

    // ---- A-tile: 32 pos x 256 ch fp32 -> bf16 fragment order ----
    #pragma unroll
    for (int i = 0; i < 16; ++i) {
        int task = i * 128 + t;              // 32 pos x 64 ch-quads = 2048
        int pl = task & 31, cg = task >> 5;
        int c0 = cg * 4;
        float v0 = fn[(c0+0) * POS_PER_CAM + pl];   // lanes = consecutive pos
        float v1 = fn[(c0+1) * POS_PER_CAM + pl];
        float v2 = fn[(c0+2) * POS_PER_CAM + pl];
        float v3 = fn[(c0+3) * POS_PER_CAM + pl];
        unsigned lo = f2bf(v0) | ((unsigned)f2bf(v1) << 16);
        unsigned hi = f2bf(v2) | ((unsigned)f2bf(v3) << 16);
        int ksp = c0 >> 5;                   // k-step 0..7
        int q   = (c0 & 31) >> 3;            // k-subgroup -> fragment-lane bits 4,5
        int lf  = (pl & 15) + (q << 4);      // fragment lane
        int f   = ((pl >> 4) * 8 + ksp) * 64 + lf;   // 16B chunk (mtile-major)
        sfo2[f * 2 + (cg & 1)] = make_uint2(lo, hi);
    }
    // ---- B-fragments: BN-folded conv_w (identical fold ops as before) ----
    #pragma unroll
    for (int i = 0; i < 20; ++i) {
        int task = i * 128 + t;              // 40 frags x 64 lanes = 2560
        int fi = task >> 6, l = task & 63;
        int nt = fi >> 3, ks = fi & 7;
        int o  = nt * 16 + (l & 15);
        int cb = ks * 32 + (l >> 4) * 8;
        float inv = 1.0f / sqrtf(var[o] + 1e-5f);
        float sc = __fmul_rn(inv, gamma[o]);
        const float* wrow = conv_w + o * C_IN + cb;
        unsigned short e[8];
        #pragma unroll
        for (int j = 0; j < 8; ++j)
            e[j] = f2bf(__fmul_rn(wrow[j], sc));
        uint4 u;
        u.x = e[0] | ((unsigned)e[1] << 16);
        u.y = e[2] | ((unsigned)e[3] << 16);
        u.z = e[4] | ((unsigned)e[5] << 16);
        u.w = e[6] | ((unsigned)e[7] << 16);
        wfrag[task] = u;
    }
    __syncthreads();

    int wv = t >> 6, l = t & 63;
    const bf16x8* sfrag = reinterpret_cast<const bf16x8*>(sfo);
    const bf16x8* wfr   = reinterpret_cast<const bf16x8*>(wfrag);
    bf16x8 a[8];
    #pragma unroll
    for (int ks = 0; ks < 8; ++ks)
        a[ks] = sfrag[(wv * 8 + ks) * 64 + l];
    int posb = b * TPOS + wv * 16 + ((l >> 4) << 2);   // D row = (l>>4)*4 + r
    #pragma unroll
    for (int nt = 0; nt < 5; ++nt) {
        f32x4 acc = {0.f, 0.f, 0.f, 0.f};
        #pragma unroll
        for (int ks = 0; ks < 8; ++ks) {     // K ascending (order-identical)
            bf16x8 bb = wfr[(nt * 8 + ks) * 64 + l];
            acc = __builtin_amdgcn_mfma_f32_16x16x32_bf16(a[ks], bb, acc, 0, 0, 0);
        }
        #pragma unroll
        for (int r = 0; r < 4; ++r)
            feat2b[(size_t)(posb + r) * C_OUT + nt * 16 + (l & 15)] = f2bf(acc[r]);
    }
}

// ---------------- kernel 2: backproject + weighted z-sum + bias + relu ----------------
// 625 blocks x 256 thr; 64 BEV columns per block. pa/bias computed inline.
__global__ __launch_bounds__(256) void k_main(const unsigned short* __restrict__ feat2b,
                                              const float* __restrict__ iam,
                                              const float* __restrict__ lam,
                                              const float* __restrict__ l2i,
                                              const float* __restrict__ conv_b,
                                              const float* __restrict__ gamma,
                                              const float* __restrict__ beta,
                                              const float* __restrict__ mean,
                                              const float* __restrict__ var,
                                              const float* __restrict__ points,
                                              float* __restrict__ out) {
    __shared__ float s_pa[84];
    __shared__ float s_bias[C_OUT];
    __shared__ int   s_base[256];
    __shared__ float s_w[256];
    __shared__ float s_y[64 * 81];   // stride 81: conflict-free transpose
    int t = threadIdx.x;
    int col0 = blockIdx.x * 64;

    // inline prep (bit-identical to old k_prep)
    if (t < N_CAM) {
        int n = t;
        const float* A = iam + n * 16;       // img_aug_matrix (last col zeroed for proj)
        const float* L = l2i + n * 16;       // lidar2image
        float M1[12];
        #pragma unroll
        for (int i = 0; i < 3; ++i)
            #pragma unroll
            for (int j = 0; j < 4; ++j) {
                float acc = __fmul_rn(A[i*4+0], L[0*4+j]);
                acc = __fmaf_rn(A[i*4+1], L[1*4+j], acc);
                acc = __fmaf_rn(A[i*4+2], L[2*4+j], acc);
                M1[i*4+j] = acc;
            }
        #pragma unroll
        for (int i = 0; i < 3; ++i)
            #pragma unroll
            for (int j = 0; j < 4; ++j) {
                float acc = __fmul_rn(M1[i*4+0], lam[0*4+j]);
                acc = __fmaf_rn(M1[i*4+1], lam[1*4+j], acc);
                acc = __fmaf_rn(M1[i*4+2], lam[2*4+j], acc);
                acc = __fmaf_rn(M1[i*4+3], lam[3*4+j], acc);
                s_pa[n*12 + i*4 + j] = acc;
            }
        s_pa[72 + n*2 + 0] = A[0*4 + 3];
        s_pa[72 + n*2 + 1] = A[1*4 + 3];
    } else if (t >= 64 && t < 64 + C_OUT) {
        int o = t - 64;
        float inv = 1.0f / sqrtf(var[o] + 1e-5f);
        float sc = __fmul_rn(inv, gamma[o]);
        s_bias[o] = __fadd_rn(__fmul_rn(__fsub_rn(conv_b[o], mean[o]), sc), beta[o]);
    }
    __syncthreads();

    // phase 1: per (column, z) camera selection — fp32 mimicking numpy op order
    {
        int cl = t & 63, z = t >> 6;
        int col = col0 + cl;
        int ix = col / NYG, iy = col % NYG;
        float x  = (float)ix * 0.5f - 50.0f;   // exact dyadic
        float y  = (float)iy * 0.5f - 50.0f;
        float zc = (float)z  * 1.5f - 4.0f;
        int sel_base = 0;
        bool any = false;
        #pragma unroll
        for (int n = 0; n < N_CAM; ++n) {
            const float* P = s_pa + n * 12;
            // sequential non-fused mul/add: matches np.einsum (no FMA, j ascending)
            float px = __fadd_rn(__fadd_rn(__fadd_rn(__fmul_rn(P[0], x), __fmul_rn(P[1], y)), __fmul_rn(P[2], zc)), P[3]);
            float py = __fadd_rn(__fadd_rn(__fadd_rn(__fmul_rn(P[4], x), __fmul_rn(P[5], y)), __fmul_rn(P[6], zc)), P[7]);
            float pz = __fadd_rn(__fadd_rn(__fadd_rn(__fmul_rn(P[8], x), __fmul_rn(P[9], y)), __fmul_rn(P[10], zc)), P[11]);
            float Z = pz;
            float Zs = (fabsf(Z) > 1e-6f) ? Z : 1e-6f;
            float u = __fadd_rn(px / Zs, s_pa[72 + n*2 + 0]);
            float v = __fadd_rn(py / Zs, s_pa[72 + n*2 + 1]);
            float uf = rintf(__fmul_rn(u, 0.125f));   // u/8 exact; rintf = half-even = np.round
            float vf = rintf(__fmul_rn(v, 0.125f));
            int ui = (int)uf, vi = (int)vf;           // saturating cvt; out-of-range stays invalid
            bool val = (ui >= 0) & (vi >= 0) & (ui < FW) & (vi < FH) & (Z > 0.0f);
            if (val) { sel_base = ((n * FH + vi) * FW + ui) * C_OUT; any = true; }  // last valid wins
        }
        float w = 0.0f;
        if (any) w = points[z * S_SPATIAL + col];   // coalesced: wave = one z plane
        else sel_base = 0;
        s_base[z * 64 + cl] = sel_base;
        s_w[z * 64 + cl] = w;
    }
    __syncthreads();

    // phase 2: vectorized gather — uint4 = 8 bf16 per task; 640 tasks
    #pragma unroll
    for (int it = 0; it < 3; ++it) {
        int task = it * 256 + t;             // 64 cols * 10 o8-groups
        if (task < 640) {
            int c = task / 10, o8 = task - c * 10;
            uint4 v0 = reinterpret_cast<const uint4*>(feat2b + s_base[0*64 + c])[o8];
            uint4 v1 = reinterpret_cast<const uint4*>(feat2b + s_base[1*64 + c])[o8];
            uint4 v2 = reinterpret_cast<const uint4*>(feat2b + s_base[2*64 + c])[o8];
            uint4 v3 = reinterpret_cast<const uint4*>(feat2b + s_base[3*64 + c])[o8];
            float w0 = s_w[0*64 + c], w1 = s_w[1*64 + c];
            float w2 = s_w[2*64 + c], w3 = s_w[3*64 + c];
            #pragma unroll
            for (int e = 0; e < 8; ++e) {
                unsigned u0 = (&v0.x)[e >> 1], u1 = (&v1.x)[e >> 1];
                unsigned u2 = (&v2.x)[e >> 1], u3 = (&v3.x)[e >> 1];
                int sh = (e & 1) << 4;
                float f0 = bf2f((unsigned short)(u0 >> sh));
                float f1 = bf2f((unsigned short)(u1 >> sh));
                float f2 = bf2f((unsigned short)(u2 >> sh));
                float f3 = bf2f((unsigned short)(u3 >> sh));
                float acc =            __fmul_rn(w0, f0);    // z ascending, same chain
                acc = __fadd_rn(acc, __fmul_rn(w1, f1));
                acc = __fadd_rn(acc, __fmul_rn(w2, f2));
                acc = __fadd_rn(acc, __fmul_rn(w3, f3));
                int o = o8 * 8 + e;
                float yv = fmaxf(__fadd_rn(acc, s_bias[o]), 0.0f);
                s_y[c * 81 + o] = yv;
            }
        }
    }
    __syncthreads();

    // phase 3: transposed write — coalesced 64-float (256B) segments per o
    #pragma unroll
    for (int it = 0; it < 20; ++it) {
        int idx = it * 256 + t;
        int o = idx >> 6, c = idx & 63;
        out[o * S_SPATIAL + col0 + c] = s_y[c * 81 + o];
    }
}

extern "C" void kernel_launch(void* const* d_in, const int* in_sizes, int n_in,
                              void* d_out, int out_size, void* d_ws, size_t ws_size,
                              hipStream_t stream) {
    const float* feat   = (const float*)d_in[0];   // (1,6,256,32,88)
    const float* points = (const float*)d_in[1];   // (1,4,200,200)
    const float* l2i    = (const float*)d_in[5];   // lidar2image (1,6,4,4)
    const float* iam    = (const float*)d_in[8];   // img_aug_matrix (1,6,4,4)
    const float* lam    = (const float*)d_in[9];   // lidar_aug_matrix (1,4,4)
    const float* conv_w = (const float*)d_in[11];  // (80,256)
    const float* conv_b = (const float*)d_in[12];
    const float* gamma  = (const float*)d_in[13];
    const float* beta   = (const float*)d_in[14];
    const float* mean   = (const float*)d_in[15];
    const float* var    = (const float*)d_in[16];

    unsigned short* feat2b = (unsigned short*)d_ws;   // NPOS*80 bf16 = 2.7 MB
    float* out = (float*)d_out;

    hipLaunchKernelGGL(k_fconv, dim3(NPOS / TPOS), dim3(128), 0, stream,
                       feat, conv_w, gamma, var, feat2b);
    hipLaunchKernelGGL(k_main, dim3(S_SPATIAL / 64), dim3(256), 0, stream,
                       feat2b, iam, lam, l2i, conv_b, gamma, beta, mean, var,
                       points, out);
}

// Round 9
// 22.699 us; speedup vs baseline: 1.1332x; 1.1332x over previous
//
#include <hip/hip_runtime.h>
#include <math.h>

typedef __attribute__((ext_vector_type(8))) short bf16x8;
typedef __attribute__((ext_vector_type(4))) float f32x4;

#define N_CAM 6
#define C_IN 256
#define C_OUT 80
#define FH 32
#define FW 88
#define NXG 200
#define NYG 200
#define S_SPATIAL (NXG*NYG)        // 40000
#define POS_PER_CAM (FH*FW)        // 2816
#define NPOS (N_CAM*POS_PER_CAM)   // 16896
#define TPOS 32                    // positions per k_fconv block

// ws layout (floats): wf B-fragments (40 KB) then feat2b (2.7 MB)
#define WS_WF     0
#define WS_FEAT2B 10240

__device__ __forceinline__ unsigned short f2bf(float f) {   // RTN-even fp32->bf16
    unsigned u = __builtin_bit_cast(unsigned, f);
    u += 0x7fffu + ((u >> 16) & 1u);
    return (unsigned short)(u >> 16);
}
__device__ __forceinline__ float bf2f(unsigned short u) {
    return __builtin_bit_cast(float, ((unsigned)u) << 16);
}

// ---------------- kernel 1: BN-folded B-fragment weights (once) ----------------
// grid 40 x 64: block = fragment fi; lane l supplies B[k=ks*32+(l>>4)*8+j][o=nt*16+(l&15)]
__global__ __launch_bounds__(64) void k_prep(const float* __restrict__ conv_w,
                                             const float* __restrict__ gamma,
                                             const float* __restrict__ var,
                                             uint4* __restrict__ wf) {
    int fi = blockIdx.x;                     // 0..39
    int t = threadIdx.x;                     // 0..63
    int nt = fi >> 3, ks = fi & 7;
    int o  = nt * 16 + (t & 15);
    int cb = ks * 32 + (t >> 4) * 8;
    float inv = 1.0f / sqrtf(var[o] + 1e-5f);
    float sc = __fmul_rn(inv, gamma[o]);
    const float* wrow = conv_w + o * C_IN + cb;
    unsigned short e[8];
    #pragma unroll
    for (int j = 0; j < 8; ++j)
        e[j] = f2bf(__fmul_rn(wrow[j], sc));
    uint4 u;
    u.x = e[0] | ((unsigned)e[1] << 16);
    u.y = e[2] | ((unsigned)e[3] << 16);
    u.z = e[4] | ((unsigned)e[5] << 16);
    u.w = e[6] | ((unsigned)e[7] << 16);
    wf[fi * 64 + t] = u;
}

// ---------------- kernel 2: fused convert/transpose + MFMA ----------------
// 528 blocks x 128 thr (2 waves); block = 32-pos tile x 256 ch.
// LDS only 16 KB (A-frags) -> ~8 blocks/CU resident; B-frags read from global wf (L2-hot).
__global__ __launch_bounds__(128) void k_fconv(const float* __restrict__ feat,
                                               const bf16x8* __restrict__ wf,
                                               unsigned short* __restrict__ feat2b) {
    __shared__ uint4 sfo[1024];              // 16 KB: 2 mtiles x 8 ks x 64 lanes
    int b = blockIdx.x, t = threadIdx.x;     // 528 = 6 cams * 88 tiles
    int n = b / 88, p0 = (b % 88) * TPOS;
    const float* fn = feat + (size_t)n * C_IN * POS_PER_CAM + p0;
    uint2* sfo2 = reinterpret_cast<uint2*>(sfo);

    // ---- A-tile: 32 pos x 256 ch fp32 -> bf16 fragment order ----
    #pragma unroll
    for (int i = 0; i < 16; ++i) {
        int task = i * 128 + t;              // 32 pos x 64 ch-quads = 2048
        int pl = task & 31, cg = task >> 5;
        int c0 = cg * 4;
        float v0 = fn[(c0+0) * POS_PER_CAM + pl];   // lanes = consecutive pos
        float v1 = fn[(c0+1) * POS_PER_CAM + pl];
        float v2 = fn[(c0+2) * POS_PER_CAM + pl];
        float v3 = fn[(c0+3) * POS_PER_CAM + pl];
        unsigned lo = f2bf(v0) | ((unsigned)f2bf(v1) << 16);
        unsigned hi = f2bf(v2) | ((unsigned)f2bf(v3) << 16);
        int ksp = c0 >> 5;                   // k-step 0..7
        int q   = (c0 & 31) >> 3;            // k-subgroup -> fragment-lane bits 4,5
        int lf  = (pl & 15) + (q << 4);      // fragment lane
        int f   = ((pl >> 4) * 8 + ksp) * 64 + lf;   // 16B chunk (mtile-major)
        sfo2[f * 2 + (cg & 1)] = make_uint2(lo, hi);
    }
    __syncthreads();

    int wv = t >> 6, l = t & 63;
    const bf16x8* sfrag = reinterpret_cast<const bf16x8*>(sfo);
    bf16x8 a[8];
    #pragma unroll
    for (int ks = 0; ks < 8; ++ks)
        a[ks] = sfrag[(wv * 8 + ks) * 64 + l];
    int posb = b * TPOS + wv * 16 + ((l >> 4) << 2);   // D row = (l>>4)*4 + r
    #pragma unroll
    for (int nt = 0; nt < 5; ++nt) {
        f32x4 acc = {0.f, 0.f, 0.f, 0.f};
        #pragma unroll
        for (int ks = 0; ks < 8; ++ks) {     // K ascending (order-identical)
            bf16x8 bb = wf[(nt * 8 + ks) * 64 + l];
            acc = __builtin_amdgcn_mfma_f32_16x16x32_bf16(a[ks], bb, acc, 0, 0, 0);
        }
        #pragma unroll
        for (int r = 0; r < 4; ++r)
            feat2b[(size_t)(posb + r) * C_OUT + nt * 16 + (l & 15)] = f2bf(acc[r]);
    }
}

// ---------------- kernel 3: backproject + weighted z-sum + bias + relu ----------------
// 625 blocks x 256 thr; 64 BEV columns per block. pa/bias computed inline.
__global__ __launch_bounds__(256) void k_main(const unsigned short* __restrict__ feat2b,
                                              const float* __restrict__ iam,
                                              const float* __restrict__ lam,
                                              const float* __restrict__ l2i,
                                              const float* __restrict__ conv_b,
                                              const float* __restrict__ gamma,
                                              const float* __restrict__ beta,
                                              const float* __restrict__ mean,
                                              const float* __restrict__ var,
                                              const float* __restrict__ points,
                                              float* __restrict__ out) {
    __shared__ float s_pa[84];
    __shared__ float s_bias[C_OUT];
    __shared__ int   s_base[256];
    __shared__ float s_w[256];
    __shared__ float s_y[64 * 81];   // stride 81: conflict-free transpose
    int t = threadIdx.x;
    int col0 = blockIdx.x * 64;

    // inline prep (bit-identical to old k_prep)
    if (t < N_CAM) {
        int n = t;
        const float* A = iam + n * 16;       // img_aug_matrix (last col zeroed for proj)
        const float* L = l2i + n * 16;       // lidar2image
        float M1[12];
        #pragma unroll
        for (int i = 0; i < 3; ++i)
            #pragma unroll
            for (int j = 0; j < 4; ++j) {
                float acc = __fmul_rn(A[i*4+0], L[0*4+j]);
                acc = __fmaf_rn(A[i*4+1], L[1*4+j], acc);
                acc = __fmaf_rn(A[i*4+2], L[2*4+j], acc);
                M1[i*4+j] = acc;
            }
        #pragma unroll
        for (int i = 0; i < 3; ++i)
            #pragma unroll
            for (int j = 0; j < 4; ++j) {
                float acc = __fmul_rn(M1[i*4+0], lam[0*4+j]);
                acc = __fmaf_rn(M1[i*4+1], lam[1*4+j], acc);
                acc = __fmaf_rn(M1[i*4+2], lam[2*4+j], acc);
                acc = __fmaf_rn(M1[i*4+3], lam[3*4+j], acc);
                s_pa[n*12 + i*4 + j] = acc;
            }
        s_pa[72 + n*2 + 0] = A[0*4 + 3];
        s_pa[72 + n*2 + 1] = A[1*4 + 3];
    } else if (t >= 64 && t < 64 + C_OUT) {
        int o = t - 64;
        float inv = 1.0f / sqrtf(var[o] + 1e-5f);
        float sc = __fmul_rn(inv, gamma[o]);
        s_bias[o] = __fadd_rn(__fmul_rn(__fsub_rn(conv_b[o], mean[o]), sc), beta[o]);
    }
    __syncthreads();

    // phase 1: per (column, z) camera selection — fp32 mimicking numpy op order
    {
        int cl = t & 63, z = t >> 6;
        int col = col0 + cl;
        int ix = col / NYG, iy = col % NYG;
        float x  = (float)ix * 0.5f - 50.0f;   // exact dyadic
        float y  = (float)iy * 0.5f - 50.0f;
        float zc = (float)z  * 1.5f - 4.0f;
        int sel_base = 0;
        bool any = false;
        #pragma unroll
        for (int n = 0; n < N_CAM; ++n) {
            const float* P = s_pa + n * 12;
            // sequential non-fused mul/add: matches np.einsum (no FMA, j ascending)
            float px = __fadd_rn(__fadd_rn(__fadd_rn(__fmul_rn(P[0], x), __fmul_rn(P[1], y)), __fmul_rn(P[2], zc)), P[3]);
            float py = __fadd_rn(__fadd_rn(__fadd_rn(__fmul_rn(P[4], x), __fmul_rn(P[5], y)), __fmul_rn(P[6], zc)), P[7]);
            float pz = __fadd_rn(__fadd_rn(__fadd_rn(__fmul_rn(P[8], x), __fmul_rn(P[9], y)), __fmul_rn(P[10], zc)), P[11]);
            float Z = pz;
            float Zs = (fabsf(Z) > 1e-6f) ? Z : 1e-6f;
            float u = __fadd_rn(px / Zs, s_pa[72 + n*2 + 0]);
            float v = __fadd_rn(py / Zs, s_pa[72 + n*2 + 1]);
            float uf = rintf(__fmul_rn(u, 0.125f));   // u/8 exact; rintf = half-even = np.round
            float vf = rintf(__fmul_rn(v, 0.125f));
            int ui = (int)uf, vi = (int)vf;           // saturating cvt; out-of-range stays invalid
            bool val = (ui >= 0) & (vi >= 0) & (ui < FW) & (vi < FH) & (Z > 0.0f);
            if (val) { sel_base = ((n * FH + vi) * FW + ui) * C_OUT; any = true; }  // last valid wins
        }
        float w = 0.0f;
        if (any) w = points[z * S_SPATIAL + col];   // coalesced: wave = one z plane
        else sel_base = 0;
        s_base[z * 64 + cl] = sel_base;
        s_w[z * 64 + cl] = w;
    }
    __syncthreads();

    // phase 2: vectorized gather — uint4 = 8 bf16 per task; 640 tasks
    #pragma unroll
    for (int it = 0; it < 3; ++it) {
        int task = it * 256 + t;             // 64 cols * 10 o8-groups
        if (task < 640) {
            int c = task / 10, o8 = task - c * 10;
            uint4 v0 = reinterpret_cast<const uint4*>(feat2b + s_base[0*64 + c])[o8];
            uint4 v1 = reinterpret_cast<const uint4*>(feat2b + s_base[1*64 + c])[o8];
            uint4 v2 = reinterpret_cast<const uint4*>(feat2b + s_base[2*64 + c])[o8];
            uint4 v3 = reinterpret_cast<const uint4*>(feat2b + s_base[3*64 + c])[o8];
            float w0 = s_w[0*64 + c], w1 = s_w[1*64 + c];
            float w2 = s_w[2*64 + c], w3 = s_w[3*64 + c];
            #pragma unroll
            for (int e = 0; e < 8; ++e) {
                unsigned u0 = (&v0.x)[e >> 1], u1 = (&v1.x)[e >> 1];
                unsigned u2 = (&v2.x)[e >> 1], u3 = (&v3.x)[e >> 1];
                int sh = (e & 1) << 4;
                float f0 = bf2f((unsigned short)(u0 >> sh));
                float f1 = bf2f((unsigned short)(u1 >> sh));
                float f2 = bf2f((unsigned short)(u2 >> sh));
                float f3 = bf2f((unsigned short)(u3 >> sh));
                float acc =            __fmul_rn(w0, f0);    // z ascending, same chain
                acc = __fadd_rn(acc, __fmul_rn(w1, f1));
                acc = __fadd_rn(acc, __fmul_rn(w2, f2));
                acc = __fadd_rn(acc, __fmul_rn(w3, f3));
                int o = o8 * 8 + e;
                float yv = fmaxf(__fadd_rn(acc, s_bias[o]), 0.0f);
                s_y[c * 81 + o] = yv;
            }
        }
    }
    __syncthreads();

    // phase 3: transposed write — coalesced 64-float (256B) segments per o
    #pragma unroll
    for (int it = 0; it < 20; ++it) {
        int idx = it * 256 + t;
        int o = idx >> 6, c = idx & 63;
        out[o * S_SPATIAL + col0 + c] = s_y[c * 81 + o];
    }
}

extern "C" void kernel_launch(void* const* d_in, const int* in_sizes, int n_in,
                              void* d_out, int out_size, void* d_ws, size_t ws_size,
                              hipStream_t stream) {
    const float* feat   = (const float*)d_in[0];   // (1,6,256,32,88)
    const float* points = (const float*)d_in[1];   // (1,4,200,200)
    const float* l2i    = (const float*)d_in[5];   // lidar2image (1,6,4,4)
    const float* iam    = (const float*)d_in[8];   // img_aug_matrix (1,6,4,4)
    const float* lam    = (const float*)d_in[9];   // lidar_aug_matrix (1,4,4)
    const float* conv_w = (const float*)d_in[11];  // (80,256)
    const float* conv_b = (const float*)d_in[12];
    const float* gamma  = (const float*)d_in[13];
    const float* beta   = (const float*)d_in[14];
    const float* mean   = (const float*)d_in[15];
    const float* var    = (const float*)d_in[16];

    float* ws = (float*)d_ws;
    uint4* wf = (uint4*)(ws + WS_WF);
    unsigned short* feat2b = (unsigned short*)(ws + WS_FEAT2B);
    float* out = (float*)d_out;

    hipLaunchKernelGGL(k_prep, dim3(40), dim3(64), 0, stream,
                       conv_w, gamma, var, wf);
    hipLaunchKernelGGL(k_fconv, dim3(NPOS / TPOS), dim3(128), 0, stream,
                       feat, (const bf16x8*)wf, feat2b);
    hipLaunchKernelGGL(k_main, dim3(S_SPATIAL / 64), dim3(256), 0, stream,
                       feat2b, iam, lam, l2i, conv_b, gamma, beta, mean, var,
                       points, out);
}